// Round 12
// baseline (181.645 us; speedup 1.0000x reference)
//
#include <hip/hip_runtime.h>
#include <hip/hip_bf16.h>
#include <math.h>

#define BDIM 512
#define DDIM 512
#define CDIM 100000
#define NC 64
#define BM 128
#define BN 128
#define BK 32
#define NKSTEP (DDIM / BK)               // 16
#define GNB 782                          // col-blocks of 128 (100096/128)
#define CPADT 100096                     // padded classes
#define NCHT (CPADT / NC)                // 1564 chunks
#define NBLK (GNB * 4)                   // 3128 blocks (4 row-blocks)
#define CTILE 128                        // classes per k_wt block

typedef __attribute__((ext_vector_type(8))) short short8;
typedef __attribute__((ext_vector_type(4))) float f32x4;

__device__ __forceinline__ unsigned short f2bf(float f) {
  unsigned int u = __builtin_bit_cast(unsigned int, f);
  u = (u + 0x7FFFu + ((u >> 16) & 1u)) >> 16;   // RNE
  return (unsigned short)u;
}

__device__ __forceinline__ void gl_lds16(const unsigned short* g, unsigned short* l) {
  __builtin_amdgcn_global_load_lds(
      (const __attribute__((address_space(1))) void*)g,
      (__attribute__((address_space(3))) void*)l, 16, 0, 0);
}

// ---- kernel 1: L2-normalize feature rows, emit bf16 [B][D] ----
__global__ void k_rownorm(const float* __restrict__ x, unsigned short* __restrict__ a) {
  const int b = blockIdx.x;
  const int tid = threadIdx.x;
  const float* row = x + (size_t)b * DDIM;
  float v0 = row[tid], v1 = row[tid + 256];
  float ss = v0 * v0 + v1 * v1;
  #pragma unroll
  for (int m = 1; m < 64; m <<= 1) ss += __shfl_xor(ss, m);
  __shared__ float sred[4];
  __shared__ float sinv;
  if ((tid & 63) == 0) sred[tid >> 6] = ss;
  __syncthreads();
  if (tid == 0) {
    float s = sred[0] + sred[1] + sred[2] + sred[3];
    sinv = 1.f / fmaxf(sqrtf(s), 1e-12f);
  }
  __syncthreads();
  const float inv = sinv;
  a[(size_t)b * DDIM + tid] = f2bf(v0 * inv);
  a[(size_t)b * DDIM + tid + 256] = f2bf(v1 * inv);
}

// ---- kernel 1b: transpose+convert w [D][C] fp32 -> w_t [CPADT][D] bf16, + invwn ----
// Proven streaming transpose (4 blocks/CU). Pad classes get zeros, invwn=1.
__global__ __launch_bounds__(512)
void k_wt(const float* __restrict__ w, unsigned short* __restrict__ wt,
          float* __restrict__ invwn) {
  __shared__ float tile[64][CTILE + 4];
  const int t = threadIdx.x;
  const int c0w = blockIdx.x * CTILE;
  const int rd_d = t >> 3;            // 0..63
  const int rd_c = (t & 7) * 16;      // col segment base
  const int wc = t >> 2;              // 0..127 class
  const int wh = t & 3;               // 0..3 d-quarter
  float ss = 0.f;

  for (int ch = 0; ch < 8; ch++) {
    const int d0 = ch * 64;
    float4 r[4];
    #pragma unroll
    for (int j = 0; j < 4; j++) {
      const int c = c0w + rd_c + j * 4;
      if (c + 3 < CDIM)
        r[j] = *reinterpret_cast<const float4*>(w + (size_t)(d0 + rd_d) * CDIM + c);
      else {
        #pragma unroll
        for (int e = 0; e < 4; e++)
          r[j][e] = (c + e < CDIM) ? w[(size_t)(d0 + rd_d) * CDIM + c + e] : 0.f;
      }
    }
    #pragma unroll
    for (int j = 0; j < 4; j++)
      *reinterpret_cast<float4*>(&tile[rd_d][rd_c + j * 4]) = r[j];
    __syncthreads();

    short8 o0, o1;
    #pragma unroll
    for (int j = 0; j < 8; j++) {
      const float v = tile[wh * 16 + j][wc];
      ss += v * v;
      o0[j] = (short)f2bf(v);
    }
    #pragma unroll
    for (int j = 0; j < 8; j++) {
      const float v = tile[wh * 16 + 8 + j][wc];
      ss += v * v;
      o1[j] = (short)f2bf(v);
    }
    {
      unsigned short* dst = wt + ((size_t)(c0w + wc) << 9) + d0 + wh * 16;
      *reinterpret_cast<short8*>(dst) = o0;       // pad classes get zeros
      *reinterpret_cast<short8*>(dst + 8) = o1;
    }
    __syncthreads();
  }
  ss += __shfl_xor(ss, 1);
  ss += __shfl_xor(ss, 2);
  if (wh == 0)
    invwn[c0w + wc] = (c0w + wc < CDIM) ? 1.f / fmaxf(sqrtf(ss), 1e-12f) : 1.f;
}

// ---- kernel 2: 128x128 GEMM, BK=32, 2-phase double-buffered pipeline ----
// 256 threads / 4 waves, 32 KB LDS -> 4 blocks/CU (16 waves). Per step:
// issue stage(s+1) FIRST (DMA to other buffer), compute(s) from current
// buffer (8 ds_read_b128 + 16 MFMA hides the load latency), then ONE
// __syncthreads (its vmcnt(0) == wait-for-stage(s+1); nothing else pending).
// Swizzle: piece ^= (row>>1)&3 -> 2-way bank aliasing (free) on reads;
// DMA dest linear (rule #21), source pre-swizzled.
__global__ __launch_bounds__(256, 4)
void k_main(const unsigned short* __restrict__ a,
            const unsigned short* __restrict__ wt,
            const float* __restrict__ invwn,
            const long long* __restrict__ label,
            float2* __restrict__ part,
            float* __restrict__ labellogit) {
  __shared__ __align__(16) unsigned short alds[2][BM * BK];   // 2 x 8 KB
  __shared__ __align__(16) unsigned short blds[2][BN * BK];   // 2 x 8 KB

  const int t = threadIdx.x;
  // bijective XCD swizzle: NBLK % 8 == 0 (3128 = 8*391)
  const int orig = (blockIdx.x & 7) * (NBLK / 8) + (blockIdx.x >> 3);
  const int rb = orig & 3;                   // row-block 0..3
  const int cb = orig >> 2;                  // col-block 0..781
  const int bm0 = rb * BM;
  const int bn0 = cb * BN;

  const int wave = t >> 6;                   // 0..3
  const int lane = t & 63;
  const int wr = wave >> 1;                  // 0..1 row-half
  const int wc = wave & 1;                   // 0..1 col-half (= chunk within cb)
  const int lhi = lane >> 4;                 // 0..3
  const int llo = lane & 15;                 // 0..15

  // staging: per gl_lds16, lanes cover 16 rows x 64B (4 pieces of 16B each);
  // lane -> row_off = lane>>2, piece = lane&3; source piece pre-swizzled.
  auto stage = [&](int s, int buf) {
    #pragma unroll
    for (int i = 0; i < 2; i++) {
      const int r = wave * 32 + i * 16 + (lane >> 2);
      const int piece = (lane & 3) ^ ((r >> 1) & 3);
      gl_lds16(a + (size_t)(bm0 + r) * DDIM + s * BK + piece * 8,
               &alds[buf][(wave * 32 + i * 16) * BK]);
      gl_lds16(wt + ((size_t)(bn0 + r) << 9) + s * BK + piece * 8,
               &blds[buf][(wave * 32 + i * 16) * BK]);
    }
  };

  f32x4 acc[4][4];
  #pragma unroll
  for (int i = 0; i < 4; i++)
    #pragma unroll
    for (int j = 0; j < 4; j++)
      acc[i][j] = (f32x4){0.f, 0.f, 0.f, 0.f};

  stage(0, 0);
  __syncthreads();                            // vmcnt(0): buf0 ready

  #pragma unroll
  for (int s = 0; s < NKSTEP; s++) {
    if (s + 1 < NKSTEP) stage(s + 1, (s + 1) & 1);  // issue-early, other buffer

    const int buf = s & 1;
    short8 af[4], bfr[4];
    #pragma unroll
    for (int m = 0; m < 4; m++) {
      const int row = wr * 64 + m * 16 + llo;
      const int pc = lhi ^ ((row >> 1) & 3);
      af[m] = *reinterpret_cast<const short8*>(&alds[buf][row * BK + pc * 8]);
    }
    #pragma unroll
    for (int n = 0; n < 4; n++) {
      const int col = wc * 64 + n * 16 + llo;
      const int pc = lhi ^ ((col >> 1) & 3);
      bfr[n] = *reinterpret_cast<const short8*>(&blds[buf][col * BK + pc * 8]);
    }
    #pragma unroll
    for (int m = 0; m < 4; m++)
      #pragma unroll
      for (int n = 0; n < 4; n++)
        acc[m][n] = __builtin_amdgcn_mfma_f32_16x16x32_bf16(af[m], bfr[n], acc[m][n], 0, 0, 0);

    __syncthreads();     // vmcnt(0) -> stage(s+1) landed; barrier -> safe swap
  }

  // ---- epilogue ----
  float inv[4];
  #pragma unroll
  for (int n = 0; n < 4; n++)
    inv[n] = invwn[bn0 + wc * 64 + n * 16 + llo];

  const int chunk = cb * 2 + wc;              // this wave's 64-col chunk
  #pragma unroll
  for (int m = 0; m < 4; m++) {
    #pragma unroll
    for (int r = 0; r < 4; r++) {
      const int row = bm0 + wr * 64 + m * 16 + (lhi << 2) + r;
      const int lab = (int)label[row];
      float vals[4];
      // finite floor (< min logit -86.4) so all-pad chunks give exp(-inf)=0, no NaN
      float mloc = -100.0f;
      #pragma unroll
      for (int n = 0; n < 4; n++) {
        const int cg = bn0 + wc * 64 + n * 16 + llo;
        float cs = acc[m][n][r] * inv[n];
        cs = fminf(fmaxf(cs, -1.f), 1.f);
        float lg = 64.f * cs;
        if (cg == lab) { lg = 64.f * (cs - 0.35f); labellogit[row] = lg; }
        if (cg >= CDIM) lg = -INFINITY;
        vals[n] = lg;
        mloc = fmaxf(mloc, lg);
      }
      float mm = mloc;
      #pragma unroll
      for (int msk = 1; msk < 16; msk <<= 1) mm = fmaxf(mm, __shfl_xor(mm, msk));
      float sacc = 0.f;
      #pragma unroll
      for (int n = 0; n < 4; n++) sacc += __expf(vals[n] - mm);
      #pragma unroll
      for (int msk = 1; msk < 16; msk <<= 1) sacc += __shfl_xor(sacc, msk);
      if (llo == 0) part[(size_t)chunk * BDIM + row] = make_float2(mm, sacc);
    }
  }
}

// ---- kernel 3: per-row online-LSE combine over chunks (part is [chunk][row]) ----
__global__ void k_rowreduce(const float2* __restrict__ part,
                            const float* __restrict__ labellogit,
                            float* __restrict__ rowloss) {
  const int row = blockIdx.x;
  const int tid = threadIdx.x;
  float m = -INFINITY, s = 0.f;
  for (int ch = tid; ch < NCHT; ch += 256) {
    float2 p = part[(size_t)ch * BDIM + row];
    float nm = fmaxf(m, p.x);
    s = s * __expf(m - nm) + p.y * __expf(p.x - nm);
    m = nm;
  }
  #pragma unroll
  for (int msk = 1; msk < 64; msk <<= 1) {
    float om = __shfl_xor(m, msk), os = __shfl_xor(s, msk);
    float nm = fmaxf(m, om);
    s = s * __expf(m - nm) + os * __expf(om - nm);
    m = nm;
  }
  __shared__ float sm[4], ssum[4];
  const int wv = tid >> 6, ln = tid & 63;
  if (ln == 0) { sm[wv] = m; ssum[wv] = s; }
  __syncthreads();
  if (tid == 0) {
    float M = sm[0], S = ssum[0];
    #pragma unroll
    for (int i = 1; i < 4; i++) {
      float nm = fmaxf(M, sm[i]);
      S = S * __expf(M - nm) + ssum[i] * __expf(sm[i] - nm);
      M = nm;
    }
    rowloss[row] = M + logf(S) - labellogit[row];
  }
}

// ---- kernel 4: mean over rows -> scalar ----
__global__ void k_mean(const float* __restrict__ rowloss, float* __restrict__ out) {
  const int tid = threadIdx.x;
  float v = rowloss[tid];
  #pragma unroll
  for (int msk = 1; msk < 64; msk <<= 1) v += __shfl_xor(v, msk);
  __shared__ float sred[8];
  if ((tid & 63) == 0) sred[tid >> 6] = v;
  __syncthreads();
  if (tid == 0) {
    float s = 0.f;
    #pragma unroll
    for (int i = 0; i < 8; i++) s += sred[i];
    out[0] = s / (float)BDIM;
  }
}

extern "C" void kernel_launch(void* const* d_in, const int* in_sizes, int n_in,
                              void* d_out, int out_size, void* d_ws, size_t ws_size,
                              hipStream_t stream) {
  const float* input = (const float*)d_in[0];
  const long long* label = (const long long*)d_in[1];
  const float* w = (const float*)d_in[2];
  float* out = (float*)d_out;

  char* ws = (char*)d_ws;
  // layout (bytes):
  //   a_bf16     @ 0         524288
  //   part       @ 524288    1564*512*8 = 6406144   (ends 6930432)
  //   labellogit @ 6930432   2048
  //   rowloss    @ 6932480   2048
  //   invwn      @ 6934528   100096*4 = 400384      (ends 7334912)
  //   w_t        @ 7334912   100096*512*2 = 102498304
  unsigned short* a_bf16 = (unsigned short*)(ws + 0);
  float2* part           = (float2*)(ws + 524288);
  float* labellogit      = (float*)(ws + 6930432);
  float* rowloss         = (float*)(ws + 6932480);
  float* invwn           = (float*)(ws + 6934528);
  unsigned short* w_t    = (unsigned short*)(ws + 7334912);

  k_rownorm<<<BDIM, 256, 0, stream>>>(input, a_bf16);
  k_wt<<<CPADT / CTILE, 512, 0, stream>>>(w, w_t, invwn);
  k_main<<<NBLK, 256, 0, stream>>>(a_bf16, w_t, invwn, label, part, labellogit);
  k_rowreduce<<<BDIM, 256, 0, stream>>>(part, labellogit, rowloss);
  k_mean<<<1, BDIM, 0, stream>>>(rowloss, out);
}